// Round 12
// baseline (218.653 us; speedup 1.0000x reference)
//
#include <hip/hip_runtime.h>
#include <math.h>

#define H 768
#define SEQ 2048
#define NSP 4096
#define HIDD 150
#define TOPK 128
#define NPAD 160

// d_out layout (floats): [0,512) mention_scores | [512,66048) ant | [66048,66560) f_starts | [66560,67072) f_ends
#define OFS_ANT 512
#define OFS_FS 66048
#define OFS_FE 66560

// workspace layout (float offsets)
static const size_t OFF_T     = 0ull;         // 11*768
static const size_t OFF_BIASP = 8448ull;      // 8*768
static const size_t OFF_WOV   = 14592ull;     // 1536
static const size_t OFF_AV    = 16128ull;     // 768
static const size_t OFF_CV    = 16896ull;     // 768
static const size_t OFF_TW    = 17664ull;     // 16
static const size_t OFF_PD    = 17680ull;     // 2*8192
static const size_t OFF_FS    = 34064ull;     // 512 ints
static const size_t OFF_FE    = 34576ull;     // 512 ints
static const size_t OFF_WID   = 35088ull;     // 512 ints
static const size_t OFF_UVP   = 35600ull;     // 2*512*320 f32
static const size_t OFF_GW    = 363280ull;    // 160
static const size_t OFF_SCAL  = 363440ull;    // 8
static const size_t OFF_WF    = 363448ull;    // 61440   (Wd f16 frags, kt-major: [24kt][10nt][64][8])
static const size_t OFF_WCF   = 424888ull;    // 122880  (UV f16 B-frags, [20nt][24kt][64][8])
static const size_t OFF_WSF   = 547768ull;    // 294912  (W_start f16 B-frags, 48nt x 24kt)
static const size_t OFF_WEF   = 842680ull;    // 294912  (W_end   f16 B-frags)
static const size_t OFF_WOF   = 1137592ull;   // 589824  (W_out   f16 B-frags, 48nt x 48kt)
static const size_t OFF_SEH   = 1727416ull;   // 1024*768 f16 = 393216 f32
static const size_t OFF_RKH   = 2120632ull;   // 512*768 f16 = 196608 f32 (row-major repr_k)
static const size_t OFF_RKP2  = 2317240ull;   // 2*512*768 f32 partials

typedef __attribute__((ext_vector_type(8))) _Float16 half8;
typedef __attribute__((ext_vector_type(4))) _Float16 half4;
typedef __attribute__((ext_vector_type(4))) float f32x4;

// ============ kP1: bias partials + WOV matvecs (408 blocks) ============
__global__ __launch_bounds__(256) void kP1(
    const float* __restrict__ b_start, const float* __restrict__ b_end,
    const float* __restrict__ b_out, const float* __restrict__ W_out,
    const float* __restrict__ w_ment,
    float* __restrict__ biasP, float* __restrict__ WOV) {
    const int blk = blockIdx.x, tid = threadIdx.x;
    if (blk < 24) {
        const int kc = blk / 3, jb = blk - kc * 3;
        const int j = jb * 256 + tid;
        float acc = (kc == 0) ? b_out[j] : 0.f;
        const int k0 = kc * 96;
#pragma unroll 4
        for (int k = k0; k < k0 + 96; ++k) {
            acc += b_start[k] * W_out[(size_t)k * H + j];
            acc += b_end[k]   * W_out[(size_t)(H + k) * H + j];
        }
        biasP[kc * H + j] = acc;
    } else {
        const int wid = tid >> 6, lane = tid & 63;
        const int gr = (blk - 24) * 4 + wid;
        const float* row = W_out + (size_t)gr * H;
        float s = 0.f;
#pragma unroll
        for (int q = 0; q < 12; ++q) s += row[lane + 64 * q] * w_ment[lane + 64 * q];
#pragma unroll
        for (int off = 32; off; off >>= 1) s += __shfl_down(s, off, 64);
        if (lane == 0) WOV[gr] = s;
    }
}

// ============ kP2: T table + av/cv (417 blocks) ============
__global__ __launch_bounds__(256) void kP2(
    const float* __restrict__ biasP, const float* __restrict__ width_emb,
    const float* __restrict__ W_out, const float* __restrict__ W_start,
    const float* __restrict__ W_end, const float* __restrict__ WOV,
    float* __restrict__ T, float* __restrict__ av, float* __restrict__ cv) {
    const int blk = blockIdx.x, tid = threadIdx.x;
    if (blk < 33) {
        const int w = blk / 3, jb = blk - w * 3;
        const int j = jb * 256 + tid;
        float acc = 0.f;
#pragma unroll
        for (int kc = 0; kc < 8; ++kc) acc += biasP[kc * H + j];
#pragma unroll
        for (int k = 0; k < 30; ++k)
            acc += width_emb[w * 30 + k] * W_out[(size_t)(2 * H + k) * H + j];
        T[w * H + j] = acc;
    } else {
        const int wid = tid >> 6, lane = tid & 63;
        const int gr = (blk - 33) * 4 + wid;
        const float* row = (gr < H) ? (W_start + (size_t)gr * H) : (W_end + (size_t)(gr - H) * H);
        const float* vec = (gr < H) ? WOV : (WOV + H);
        float s = 0.f;
#pragma unroll
        for (int q = 0; q < 12; ++q) s += row[lane + 64 * q] * vec[lane + 64 * q];
#pragma unroll
        for (int off = 32; off; off >>= 1) s += __shfl_down(s, off, 64);
        if (lane == 0) {
            if (gr < H) av[gr] = s; else cv[gr - H] = s;
        }
    }
}

// ============ kPost: posdots + tw + all weight conversions + GW/SCAL + ant-zero
// blocks: [0,2048) posdots | 2048 tw | [2049,2109) WF | [2109,2229) WCF |
// [2229,2517) WSF | [2517,2805) WEF | [2805,3381) WOF | 3381 GW | [3382,3446) ant0
__global__ __launch_bounds__(256) void kPost(
    const float* __restrict__ seq, const float* __restrict__ av,
    const float* __restrict__ cv, const float* __restrict__ T,
    const float* __restrict__ w_ment, const float* __restrict__ b_ment,
    const float* __restrict__ W1, const float* __restrict__ W_start,
    const float* __restrict__ W_end, const float* __restrict__ W_out,
    const float* __restrict__ ln_g, const float* __restrict__ ln_b,
    const float* __restrict__ W2, const float* __restrict__ b2,
    float* __restrict__ PD, float* __restrict__ tw,
    _Float16* __restrict__ WF, _Float16* __restrict__ WCF,
    _Float16* __restrict__ WSF, _Float16* __restrict__ WEF,
    _Float16* __restrict__ WOF, float* __restrict__ GW, float* __restrict__ SCAL,
    float* __restrict__ ant) {
    const int blk = blockIdx.x, tid = threadIdx.x;
    const int wid = tid >> 6, lane = tid & 63;
    if (blk < 2048) {
        const int r = blk * 4 + wid;
        const float4* row = (const float4*)(seq + (size_t)r * H);
        const float4* a4 = (const float4*)av;
        const float4* c4 = (const float4*)cv;
        float sa = 0.f, sc = 0.f;
#pragma unroll
        for (int q = 0; q < 3; ++q) {
            float4 x = row[lane + 64 * q];
            float4 ya = a4[lane + 64 * q], yc = c4[lane + 64 * q];
            sa += x.x * ya.x + x.y * ya.y + x.z * ya.z + x.w * ya.w;
            sc += x.x * yc.x + x.y * yc.y + x.z * yc.z + x.w * yc.w;
        }
#pragma unroll
        for (int off = 32; off; off >>= 1) {
            sa += __shfl_down(sa, off, 64);
            sc += __shfl_down(sc, off, 64);
        }
        if (lane == 0) { PD[r] = sa; PD[8192 + r] = sc; }
    } else if (blk == 2048) {
        for (int w = wid; w <= 10; w += 4) {
            float s = 0.f;
#pragma unroll
            for (int q = 0; q < 12; ++q) s += T[w * H + lane + 64 * q] * w_ment[lane + 64 * q];
#pragma unroll
            for (int off = 32; off; off >>= 1) s += __shfl_down(s, off, 64);
            if (lane == 0) tw[w] = s + b_ment[0];
        }
    } else if (blk < 2109) {
        // WF: kt-major layout [kt][nt][lane][8]
        const int idx = (blk - 2049) * 256 + tid;
        const int nt = idx / 1536;
        const int rem = idx - nt * 1536;
        const int kt = rem >> 6, ln = rem & 63;
        const int n = nt * 16 + (ln & 15);
        const int kb = kt * 32 + (ln >> 4) * 8;
        _Float16* dst = WF + ((size_t)((kt * 10 + nt) * 64 + ln)) * 8;
#pragma unroll
        for (int e = 0; e < 8; ++e) {
            float v = (n < HIDD) ? W1[(size_t)(3 * H + kb + e) * HIDD + n] : 0.f;
            dst[e] = (_Float16)v;
        }
    } else if (blk < 2229) {
        const int idx = (blk - 2109) * 256 + tid;
        const int nt = idx / 1536;
        const int rem = idx - nt * 1536;
        const int kt = rem >> 6, ln = rem & 63;
        const int n = nt * 16 + (ln & 15);
        const int kb = kt * 32 + (ln >> 4) * 8;
        _Float16* dst = WCF + (size_t)idx * 8;
#pragma unroll
        for (int e = 0; e < 8; ++e) {
            const int h = kb + e;
            float v = 0.f;
            if (n < 160) {
                if (n < HIDD)
                    v = W1[(size_t)h * HIDD + n] + W1[(size_t)(2 * H + h) * HIDD + n];
            } else {
                const int d = n - 160;
                if (d < HIDD)
                    v = W1[(size_t)(H + h) * HIDD + d] - W1[(size_t)(2 * H + h) * HIDD + d];
            }
            dst[e] = (_Float16)v;
        }
    } else if (blk < 2805) {
        const bool isS = blk < 2517;
        const int idx = (blk - (isS ? 2229 : 2517)) * 256 + tid;
        const float* Wsrc = isS ? W_start : W_end;
        _Float16* dstb = isS ? WSF : WEF;
        const int nt = idx / 1536;
        const int rem = idx - nt * 1536;
        const int kt = rem >> 6, ln = rem & 63;
        const int n = nt * 16 + (ln & 15);
        const int kb = kt * 32 + (ln >> 4) * 8;
        _Float16* dst = dstb + (size_t)idx * 8;
#pragma unroll
        for (int e = 0; e < 8; ++e) dst[e] = (_Float16)Wsrc[(size_t)(kb + e) * H + n];
    } else if (blk < 3381) {
        const int idx = (blk - 2805) * 256 + tid;
        const int nt = idx / 3072;
        const int rem = idx - nt * 3072;
        const int kt = rem >> 6, ln = rem & 63;
        const int n = nt * 16 + (ln & 15);
        const int kb = kt * 32 + (ln >> 4) * 8;
        _Float16* dst = WOF + (size_t)idx * 8;
#pragma unroll
        for (int e = 0; e < 8; ++e) dst[e] = (_Float16)W_out[(size_t)(kb + e) * H + n];
    } else if (blk == 3381) {
        if (tid < NPAD) GW[tid] = (tid < HIDD) ? ln_g[tid] * W2[tid] : 0.f;
        if (tid == 0) {
            float sg = 0.f, sb = 0.f;
            for (int d = 0; d < HIDD; ++d) { sg += ln_g[d] * W2[d]; sb += ln_b[d] * W2[d]; }
            SCAL[0] = sg;
            SCAL[1] = sb + b2[0];
        }
    } else {
        const int idx = (blk - 3382) * 256 + tid;
        *(float4*)(ant + (size_t)idx * 4) = make_float4(0.f, 0.f, 0.f, 0.f);
    }
}

// ============ k_sort: fused top-128 per batch (4 blocks x 1024 thr) ============
// phase A: 8 parallel chunk-local 512-bitonic sorts (desc); B: compact top-128s;
// C: 3-round bitonic top-k merge; emit outputs.
__global__ __launch_bounds__(1024) void k_sort(const float* __restrict__ PD,
    const int* __restrict__ starts, const int* __restrict__ ends,
    const float* __restrict__ tw, float* __restrict__ out,
    int* __restrict__ fsI, int* __restrict__ feI, int* __restrict__ widI) {
    __shared__ unsigned long long K[4096];
    const int b = blockIdx.x, tid = threadIdx.x;
    for (int i = tid; i < 4096; i += 1024) {
        const int r = b * NSP + i;
        const int s = starts[r], e = ends[r];
        int w = e - s; w = w < 0 ? 0 : (w > 10 ? 10 : w);
        const float sc = PD[b * SEQ + s] + PD[8192 + b * SEQ + e] + tw[w];
        unsigned u = __float_as_uint(sc);
        u = (u & 0x80000000u) ? ~u : (u | 0x80000000u);
        K[i] = ((unsigned long long)u << 32) | (unsigned)(0xFFFFFFFFu - (unsigned)i);
    }
    __syncthreads();
    // A: chunk-local bitonic (8 chunks x 512, all in lockstep)
    for (int k = 2; k <= 512; k <<= 1) {
        for (int j = k >> 1; j > 0; j >>= 1) {
#pragma unroll
            for (int pp = 0; pp < 2; ++pp) {
                const int p = tid + pp * 1024;
                const int c = p >> 8, r = p & 255;
                const int il = ((r & ~(j - 1)) << 1) | (r & (j - 1));
                const int lo = c * 512 + il, hi = lo + j;
                unsigned long long a = K[lo], d = K[hi];
                const bool desc = ((il & k) == 0);
                if ((a < d) == desc) { K[lo] = d; K[hi] = a; }
            }
            __syncthreads();
        }
    }
    // B: compact chunk-top-128s to K[0..1024)
    unsigned long long v = K[(tid >> 7) * 512 + (tid & 127)];
    __syncthreads();
    K[tid] = v;
    __syncthreads();
    // C: merge 8 sorted-desc 128-lists
    for (int nl = 4; nl >= 1; nl >>= 1) {
        const int items = nl * 128;
        unsigned long long v0 = 0;
        if (tid < items) {
            const int q = tid >> 7, r = tid & 127;
            unsigned long long a = K[q * 256 + r];
            unsigned long long d = K[q * 256 + 128 + (127 - r)];
            v0 = a > d ? a : d;
        }
        __syncthreads();
        if (tid < items) K[(tid >> 7) * 128 + (tid & 127)] = v0;
        __syncthreads();
        for (int j = 64; j; j >>= 1) {
            const int pairs = nl * 64;
            if (tid < pairs) {
                const int q = tid >> 6, r = tid & 63;
                const int lo = q * 128 + (((r & ~(j - 1)) << 1) | (r & (j - 1)));
                const int hi = lo + j;
                unsigned long long a = K[lo], d = K[hi];
                if (a < d) { K[lo] = d; K[hi] = a; }
            }
            __syncthreads();
        }
    }
    if (tid < TOPK) {
        const unsigned long long key = K[tid];
        const int widx = (int)(0xFFFFFFFFu - (unsigned)(key & 0xFFFFFFFFu));
        const unsigned hu = (unsigned)(key >> 32);
        const float sval = __uint_as_float((hu & 0x80000000u) ? (hu & 0x7FFFFFFFu) : ~hu);
        const int s = starts[b * NSP + widx], e = ends[b * NSP + widx];
        const int p = b * TOPK + tid;
        out[p] = sval;
        out[OFS_FS + p] = (float)s;
        out[OFS_FE + p] = (float)e;
        fsI[p] = b * SEQ + s;
        feI[p] = b * SEQ + e;
        int w = e - s;
        widI[p] = w < 0 ? 0 : (w > 10 ? 10 : w);
    }
}

// SEH(1024x768) = gathered-seq @ [W_start | W_end], fused gather + cvt, reg-pipelined.
__global__ __launch_bounds__(256) void k_gemm1(const float* __restrict__ seq,
    const int* __restrict__ fsI, const int* __restrict__ feI,
    const _Float16* __restrict__ WSF, const _Float16* __restrict__ WEF,
    _Float16* __restrict__ SEH) {
    const int mt = blockIdx.x;
    const int wave = threadIdx.x >> 6, lane = threadIdx.x & 63;
    const int g = lane >> 4;
    const int nt0 = blockIdx.y * 8 + wave * 2;
    const int gi = mt * 16 + (lane & 15);
    const int src = (mt < 32) ? fsI[gi] : feI[gi - 512];
    const float* Arow = seq + (size_t)src * H + g * 8;
    const _Float16* BF = (mt < 32) ? WSF : WEF;
    f32x4 acc0 = {0.f, 0.f, 0.f, 0.f}, acc1 = acc0;
    float4 v0 = *(const float4*)(Arow);
    float4 v1 = *(const float4*)(Arow + 4);
    half8 b0 = *(const half8*)(BF + ((size_t)(nt0 * 24) * 64 + lane) * 8);
    half8 b1 = *(const half8*)(BF + ((size_t)((nt0 + 1) * 24) * 64 + lane) * 8);
    for (int kt = 0; kt < 24; ++kt) {
        float4 nv0, nv1;
        half8 nb0, nb1;
        if (kt < 23) {
            nv0 = *(const float4*)(Arow + (kt + 1) * 32);
            nv1 = *(const float4*)(Arow + (kt + 1) * 32 + 4);
            nb0 = *(const half8*)(BF + ((size_t)(nt0 * 24 + kt + 1) * 64 + lane) * 8);
            nb1 = *(const half8*)(BF + ((size_t)((nt0 + 1) * 24 + kt + 1) * 64 + lane) * 8);
        }
        half8 a = {(_Float16)v0.x, (_Float16)v0.y, (_Float16)v0.z, (_Float16)v0.w,
                   (_Float16)v1.x, (_Float16)v1.y, (_Float16)v1.z, (_Float16)v1.w};
        acc0 = __builtin_amdgcn_mfma_f32_16x16x32_f16(a, b0, acc0, 0, 0, 0);
        acc1 = __builtin_amdgcn_mfma_f32_16x16x32_f16(a, b1, acc1, 0, 0, 0);
        if (kt < 23) { v0 = nv0; v1 = nv1; b0 = nb0; b1 = nb1; }
    }
    const int c = lane & 15, quad = lane >> 4;
#pragma unroll
    for (int r = 0; r < 4; ++r) {
        const int row = mt * 16 + quad * 4 + r;
        SEH[(size_t)row * H + nt0 * 16 + c] = (_Float16)acc0[r];
        SEH[(size_t)row * H + (nt0 + 1) * 16 + c] = (_Float16)acc1[r];
    }
}

// RKP2[kh] = SEH-half @ W_out-half via f16 MFMA, reg-pipelined. grid (32, 6, 2)
__global__ __launch_bounds__(256) void k_gemm2(const _Float16* __restrict__ SEH,
    const _Float16* __restrict__ WOF, float* __restrict__ RKP2) {
    const int mt = blockIdx.x, kh = blockIdx.z;
    const int wave = threadIdx.x >> 6, lane = threadIdx.x & 63;
    const int nt0 = blockIdx.y * 8 + wave * 2;
    const _Float16* Arow = SEH + (size_t)(kh * 512 + mt * 16 + (lane & 15)) * H + (lane >> 4) * 8;
    const _Float16* B0 = WOF + ((size_t)(nt0 * 48 + kh * 24) * 64 + lane) * 8;
    const _Float16* B1 = WOF + ((size_t)((nt0 + 1) * 48 + kh * 24) * 64 + lane) * 8;
    f32x4 acc0 = {0.f, 0.f, 0.f, 0.f}, acc1 = acc0;
    half8 a = *(const half8*)(Arow);
    half8 b0 = *(const half8*)(B0);
    half8 b1 = *(const half8*)(B1);
    for (int kt2 = 0; kt2 < 24; ++kt2) {
        half8 na, nb0, nb1;
        if (kt2 < 23) {
            na = *(const half8*)(Arow + (kt2 + 1) * 32);
            nb0 = *(const half8*)(B0 + (size_t)(kt2 + 1) * 512);
            nb1 = *(const half8*)(B1 + (size_t)(kt2 + 1) * 512);
        }
        acc0 = __builtin_amdgcn_mfma_f32_16x16x32_f16(a, b0, acc0, 0, 0, 0);
        acc1 = __builtin_amdgcn_mfma_f32_16x16x32_f16(a, b1, acc1, 0, 0, 0);
        if (kt2 < 23) { a = na; b0 = nb0; b1 = nb1; }
    }
    const int c = lane & 15, quad = lane >> 4;
    float* dst = RKP2 + (size_t)kh * 512 * H;
#pragma unroll
    for (int r = 0; r < 4; ++r) {
        const int row = mt * 16 + quad * 4 + r;
        dst[(size_t)row * H + nt0 * 16 + c] = acc0[r];
        dst[(size_t)row * H + (nt0 + 1) * 16 + c] = acc1[r];
    }
}

// U/V partials via f16 MFMA with FUSED fin: block (t,kh) reconstructs its 16x384
// RKH half from RKP2+T into LDS (and writes it to global for k_pair), then MFMAs.
__global__ __launch_bounds__(256) void k_uv3(const float* __restrict__ RKP2,
    const float* __restrict__ T, const int* __restrict__ widI,
    const _Float16* __restrict__ WCF, _Float16* __restrict__ RKH,
    float* __restrict__ UVP) {
    const int t = blockIdx.x, kh = blockIdx.y;
    const int tid = threadIdx.x;
    __shared__ _Float16 sA[16][392];   // stride 392 halves -> 2-way-free banks
    // fin: 16 rows x 384 cols (this kh half)
    for (int idx = tid; idx < 16 * 96; idx += 256) {
        const int row = idx / 96, c4 = idx - row * 96;
        const int p = t * 16 + row;
        const int col = kh * 384 + c4 * 4;
        float4 s = *(const float4*)(T + (size_t)widI[p] * H + col);
        float4 v0 = *(const float4*)(RKP2 + (size_t)p * H + col);
        float4 v1 = *(const float4*)(RKP2 + (size_t)(512 + p) * H + col);
        half4 h = {(_Float16)(s.x + v0.x + v1.x), (_Float16)(s.y + v0.y + v1.y),
                   (_Float16)(s.z + v0.z + v1.z), (_Float16)(s.w + v0.w + v1.w)};
        *(half4*)&sA[row][c4 * 4] = h;
        *(half4*)(RKH + (size_t)p * H + col) = h;
    }
    __syncthreads();
    const int wave = tid >> 6, lane = tid & 63;
    const int m = lane & 15, g = lane >> 4;
    f32x4 acc[5];
#pragma unroll
    for (int q = 0; q < 5; ++q) acc[q] = (f32x4){0.f, 0.f, 0.f, 0.f};
    half8 bv[5], nbv[5];
#pragma unroll
    for (int q = 0; q < 5; ++q)
        bv[q] = *(const half8*)(WCF + ((size_t)(((wave * 5 + q) * 24 + kh * 12) * 64 + lane)) * 8);
    for (int kk = 0; kk < 12; ++kk) {
        if (kk < 11) {
            const int kt = kh * 12 + kk + 1;
#pragma unroll
            for (int q = 0; q < 5; ++q)
                nbv[q] = *(const half8*)(WCF + ((size_t)(((wave * 5 + q) * 24 + kt) * 64 + lane)) * 8);
        }
        half8 a = *(const half8*)&sA[m][kk * 32 + g * 8];
#pragma unroll
        for (int q = 0; q < 5; ++q)
            acc[q] = __builtin_amdgcn_mfma_f32_16x16x32_f16(a, bv[q], acc[q], 0, 0, 0);
        if (kk < 11) {
#pragma unroll
            for (int q = 0; q < 5; ++q) bv[q] = nbv[q];
        }
    }
    const int c = lane & 15;
#pragma unroll
    for (int q = 0; q < 5; ++q) {
        const int n = (wave * 5 + q) * 16 + c;
#pragma unroll
        for (int r = 0; r < 4; ++r) {
            const int p = t * 16 + g * 4 + r;
            UVP[((size_t)kh * 512 + p) * 320 + n] = acc[q][r];
        }
    }
}

// Pairwise MFMA: 8i x 16j triangular tile, no LDS/barriers, register pipeline.
__global__ __launch_bounds__(256, 1) void k_pair(
    const _Float16* __restrict__ WF, const _Float16* __restrict__ RKH,
    const float* __restrict__ UVP, const float* __restrict__ b1,
    const float* __restrict__ GW, const float* __restrict__ SCAL,
    float* __restrict__ ant) {
    const int b = blockIdx.y;
    int ti = 0, rem = blockIdx.x;
    while (rem >= (ti >> 1) + 1) { rem -= (ti >> 1) + 1; ++ti; }
    const int tj = rem;
    const int wave = threadIdx.x >> 6, lane = threadIdx.x & 63;
    const int g = lane >> 4, c = lane & 15;
    const int i0 = ti * 8 + wave * 2;
    const int j0 = tj * 16;

    const _Float16* Ri0 = RKH + (size_t)(b * TOPK + i0) * H + g * 8;
    const _Float16* Ri1 = RKH + (size_t)(b * TOPK + i0 + 1) * H + g * 8;
    const _Float16* Rj  = RKH + (size_t)(b * TOPK + j0 + c) * H + g * 8;
    const _Float16* Wl  = WF + (size_t)lane * 8;

    f32x4 acc0[10], acc1[10];
#pragma unroll
    for (int nt = 0; nt < 10; ++nt) {
        acc0[nt] = (f32x4){0.f, 0.f, 0.f, 0.f};
        acc1[nt] = (f32x4){0.f, 0.f, 0.f, 0.f};
    }

    half8 bv[10], nbv[10];
    half8 rj, ri0, ri1, nrj, nri0, nri1;
#pragma unroll
    for (int nt = 0; nt < 10; ++nt) bv[nt] = *(const half8*)(Wl + (size_t)nt * 512);
    rj  = *(const half8*)(Rj);
    ri0 = *(const half8*)(Ri0);
    ri1 = *(const half8*)(Ri1);

    for (int kt = 0; kt < 24; ++kt) {
        if (kt < 23) {
            const _Float16* wsrc = Wl + (size_t)(kt + 1) * 5120;
#pragma unroll
            for (int nt = 0; nt < 10; ++nt) nbv[nt] = *(const half8*)(wsrc + (size_t)nt * 512);
            nrj  = *(const half8*)(Rj + (kt + 1) * 32);
            nri0 = *(const half8*)(Ri0 + (kt + 1) * 32);
            nri1 = *(const half8*)(Ri1 + (kt + 1) * 32);
        }
        half8 a0 = ri0 * rj;
        half8 a1 = ri1 * rj;
#pragma unroll
        for (int nt = 0; nt < 10; ++nt) {
            acc0[nt] = __builtin_amdgcn_mfma_f32_16x16x32_f16(a0, bv[nt], acc0[nt], 0, 0, 0);
            acc1[nt] = __builtin_amdgcn_mfma_f32_16x16x32_f16(a1, bv[nt], acc1[nt], 0, 0, 0);
        }
        if (kt < 23) {
#pragma unroll
            for (int nt = 0; nt < 10; ++nt) bv[nt] = nbv[nt];
            rj = nrj; ri0 = nri0; ri1 = nri1;
        }
    }

    const float Sgw = SCAL[0], C0 = SCAL[1];
    float gw10[10];
#pragma unroll
    for (int nt = 0; nt < 10; ++nt) gw10[nt] = GW[nt * 16 + c];

#pragma unroll
    for (int iw = 0; iw < 2; ++iw) {
        const int i = i0 + iw;
        const int pi = b * TOPK + i;
        float u10[10];
#pragma unroll
        for (int nt = 0; nt < 10; ++nt) {
            const int d = nt * 16 + c;
            const float ub = (d < HIDD) ? b1[d] : 0.f;
            u10[nt] = UVP[(size_t)pi * 320 + d] + UVP[(size_t)(512 + pi) * 320 + d] + ub;
        }
        const f32x4* acc = iw ? acc1 : acc0;
#pragma unroll
        for (int r = 0; r < 4; ++r) {
            const int j = j0 + g * 4 + r;
            const int pj = b * TOPK + j;
            const float* Vp0 = UVP + (size_t)pj * 320 + 160;
            const float* Vp1 = UVP + (size_t)(512 + pj) * 320 + 160;
            float s1 = 0.f, s2 = 0.f, s3 = 0.f;
#pragma unroll
            for (int nt = 0; nt < 10; ++nt) {
                const int d = nt * 16 + c;
                float z = acc[nt][r] + u10[nt] + Vp0[d] + Vp1[d];
                float h = (d < HIDD && z > 0.f) ? z : 0.f;
                s1 += h;
                s2 += h * h;
                s3 += h * gw10[nt];
            }
#pragma unroll
            for (int off = 1; off < 16; off <<= 1) {
                s1 += __shfl_xor(s1, off, 64);
                s2 += __shfl_xor(s2, off, 64);
                s3 += __shfl_xor(s3, off, 64);
            }
            const float mu = s1 * (1.f / HIDD);
            const float var = s2 * (1.f / HIDD) - mu * mu;
            const float rstd = rsqrtf(var + 1e-5f);
            const float val = rstd * (s3 - mu * Sgw) + C0;
            if (c == 0 && j < i) ant[((size_t)b * TOPK + i) * TOPK + j] = val;
        }
    }
}

extern "C" void kernel_launch(void* const* d_in, const int* in_sizes, int n_in,
                              void* d_out, int out_size, void* d_ws, size_t ws_size,
                              hipStream_t stream) {
    const float* seq      = (const float*)d_in[0];
    const int*   starts   = (const int*)d_in[1];
    const int*   ends     = (const int*)d_in[2];
    const float* W_start  = (const float*)d_in[3];
    const float* b_start  = (const float*)d_in[4];
    const float* W_end    = (const float*)d_in[5];
    const float* b_end    = (const float*)d_in[6];
    const float* width_e  = (const float*)d_in[7];
    const float* W_out    = (const float*)d_in[8];
    const float* b_out    = (const float*)d_in[9];
    const float* w_ment   = (const float*)d_in[10];
    const float* b_ment   = (const float*)d_in[11];
    const float* W1       = (const float*)d_in[12];
    const float* b1       = (const float*)d_in[13];
    const float* ln_g     = (const float*)d_in[14];
    const float* ln_b     = (const float*)d_in[15];
    const float* W2       = (const float*)d_in[16];
    const float* b2       = (const float*)d_in[17];
    float* out = (float*)d_out;
    float* ws  = (float*)d_ws;

    float* Tt    = ws + OFF_T;
    float* biasP = ws + OFF_BIASP;
    float* WOV   = ws + OFF_WOV;
    float* av    = ws + OFF_AV;
    float* cv    = ws + OFF_CV;
    float* tw    = ws + OFF_TW;
    float* PD    = ws + OFF_PD;
    int*   fsI   = (int*)(ws + OFF_FS);
    int*   feI   = (int*)(ws + OFF_FE);
    int*   widI  = (int*)(ws + OFF_WID);
    float* UVPp  = ws + OFF_UVP;
    float* GWp   = ws + OFF_GW;
    float* SCALp = ws + OFF_SCAL;
    _Float16* WFp   = (_Float16*)(ws + OFF_WF);
    _Float16* WCFp  = (_Float16*)(ws + OFF_WCF);
    _Float16* WSFp  = (_Float16*)(ws + OFF_WSF);
    _Float16* WEFp  = (_Float16*)(ws + OFF_WEF);
    _Float16* WOFp  = (_Float16*)(ws + OFF_WOF);
    _Float16* SEHp  = (_Float16*)(ws + OFF_SEH);
    _Float16* RKHp  = (_Float16*)(ws + OFF_RKH);
    float* RKP2p = ws + OFF_RKP2;

    kP1<<<408, 256, 0, stream>>>(b_start, b_end, b_out, W_out, w_ment, biasP, WOV);
    kP2<<<417, 256, 0, stream>>>(biasP, width_e, W_out, W_start, W_end, WOV, Tt, av, cv);
    kPost<<<3446, 256, 0, stream>>>(seq, av, cv, Tt, w_ment, b_ment, W1, W_start, W_end,
                                    W_out, ln_g, ln_b, W2, b2, PD, tw,
                                    WFp, WCFp, WSFp, WEFp, WOFp, GWp, SCALp,
                                    out + OFS_ANT);
    k_sort<<<4, 1024, 0, stream>>>(PD, starts, ends, tw, out, fsI, feI, widI);
    k_gemm1<<<dim3(64, 6), 256, 0, stream>>>(seq, fsI, feI, WSFp, WEFp, SEHp);
    k_gemm2<<<dim3(32, 6, 2), 256, 0, stream>>>(SEHp, WOFp, RKP2p);
    k_uv3<<<dim3(32, 2), 256, 0, stream>>>(RKP2p, Tt, widI, WCFp, RKHp, UVPp);
    k_pair<<<dim3(72, 4), 256, 0, stream>>>(WFp, RKHp, UVPp, b1, GWp, SCALp,
                                            out + OFS_ANT);
}

// Round 13
// 200.757 us; speedup vs baseline: 1.0891x; 1.0891x over previous
//
#include <hip/hip_runtime.h>
#include <math.h>

#define H 768
#define SEQ 2048
#define NSP 4096
#define HIDD 150
#define TOPK 128
#define NPAD 160

// d_out layout (floats): [0,512) mention_scores | [512,66048) ant | [66048,66560) f_starts | [66560,67072) f_ends
#define OFS_ANT 512
#define OFS_FS 66048
#define OFS_FE 66560

// workspace layout (float offsets)
static const size_t OFF_T     = 0ull;         // 11*768
static const size_t OFF_BIASP = 8448ull;      // 8*768
static const size_t OFF_WOV   = 14592ull;     // 1536
static const size_t OFF_AV    = 16128ull;     // 768
static const size_t OFF_CV    = 16896ull;     // 768
static const size_t OFF_TW    = 17664ull;     // 16
static const size_t OFF_PD    = 17680ull;     // 2*8192
static const size_t OFF_CAND  = 34064ull;     // 4096 u64 = 8192 f32 (even -> 8B aligned)
static const size_t OFF_FS    = 42256ull;     // 512 ints
static const size_t OFF_FE    = 42768ull;     // 512 ints
static const size_t OFF_WID   = 43280ull;     // 512 ints
static const size_t OFF_UVP   = 43792ull;     // 2*512*320 f32
static const size_t OFF_GW    = 371472ull;    // 160
static const size_t OFF_SCAL  = 371632ull;    // 8
static const size_t OFF_WF    = 371640ull;    // 61440   (Wd f16 frags, kt-major: [24kt][10nt][64][8])
static const size_t OFF_WCF   = 433080ull;    // 122880  (UV f16 B-frags, [20nt][24kt][64][8])
static const size_t OFF_WSF   = 555960ull;    // 294912  (W_start f16 B-frags, 48nt x 24kt)
static const size_t OFF_WEF   = 850872ull;    // 294912  (W_end   f16 B-frags)
static const size_t OFF_WOF   = 1145784ull;   // 589824  (W_out   f16 B-frags, 48nt x 48kt)
static const size_t OFF_SEH   = 1735608ull;   // 1024*768 f16 = 393216 f32
static const size_t OFF_RKH   = 2128824ull;   // 512*768 f16 = 196608 f32 (row-major repr_k)
static const size_t OFF_RKP2  = 2325432ull;   // 2*512*768 f32 partials

typedef __attribute__((ext_vector_type(8))) _Float16 half8;
typedef __attribute__((ext_vector_type(4))) _Float16 half4;
typedef __attribute__((ext_vector_type(4))) float f32x4;

// ============ kA: independent preps (1805 blocks) ============
__global__ __launch_bounds__(256) void kA(
    const float* __restrict__ b_start, const float* __restrict__ b_end,
    const float* __restrict__ b_out, const float* __restrict__ W_out,
    const float* __restrict__ w_ment, const float* __restrict__ W1,
    const float* __restrict__ ln_g, const float* __restrict__ ln_b,
    const float* __restrict__ W2, const float* __restrict__ b2,
    const float* __restrict__ W_start, const float* __restrict__ W_end,
    float* __restrict__ biasP, float* __restrict__ WOV,
    _Float16* __restrict__ WF, _Float16* __restrict__ WCF,
    _Float16* __restrict__ WSF, _Float16* __restrict__ WEF,
    _Float16* __restrict__ WOF, float* __restrict__ GW, float* __restrict__ SCAL,
    float* __restrict__ ant) {
    const int blk = blockIdx.x, tid = threadIdx.x;
    if (blk < 24) {
        const int kc = blk / 3, jb = blk - kc * 3;
        const int j = jb * 256 + tid;
        float acc = (kc == 0) ? b_out[j] : 0.f;
        const int k0 = kc * 96;
#pragma unroll 4
        for (int k = k0; k < k0 + 96; ++k) {
            acc += b_start[k] * W_out[(size_t)k * H + j];
            acc += b_end[k]   * W_out[(size_t)(H + k) * H + j];
        }
        biasP[kc * H + j] = acc;
    } else if (blk < 408) {
        const int wid = tid >> 6, lane = tid & 63;
        const int gr = (blk - 24) * 4 + wid;
        const float* row = W_out + (size_t)gr * H;
        float s = 0.f;
#pragma unroll
        for (int q = 0; q < 12; ++q) s += row[lane + 64 * q] * w_ment[lane + 64 * q];
#pragma unroll
        for (int off = 32; off; off >>= 1) s += __shfl_down(s, off, 64);
        if (lane == 0) WOV[gr] = s;
    } else if (blk < 468) {
        // WF: kt-major layout [kt][nt][lane][8]
        const int idx = (blk - 408) * 256 + tid;
        const int nt = idx / 1536;
        const int rem = idx - nt * 1536;
        const int kt = rem >> 6, lane = rem & 63;
        const int n = nt * 16 + (lane & 15);
        const int kb = kt * 32 + (lane >> 4) * 8;
        _Float16* dst = WF + ((size_t)((kt * 10 + nt) * 64 + lane)) * 8;
#pragma unroll
        for (int e = 0; e < 8; ++e) {
            float v = (n < HIDD) ? W1[(size_t)(3 * H + kb + e) * HIDD + n] : 0.f;
            dst[e] = (_Float16)v;
        }
    } else if (blk < 588) {
        const int idx = (blk - 468) * 256 + tid;
        const int nt = idx / 1536;
        const int rem = idx - nt * 1536;
        const int kt = rem >> 6, lane = rem & 63;
        const int n = nt * 16 + (lane & 15);
        const int kb = kt * 32 + (lane >> 4) * 8;
        _Float16* dst = WCF + (size_t)idx * 8;
#pragma unroll
        for (int e = 0; e < 8; ++e) {
            const int h = kb + e;
            float v = 0.f;
            if (n < 160) {
                if (n < HIDD)
                    v = W1[(size_t)h * HIDD + n] + W1[(size_t)(2 * H + h) * HIDD + n];
            } else {
                const int d = n - 160;
                if (d < HIDD)
                    v = W1[(size_t)(H + h) * HIDD + d] - W1[(size_t)(2 * H + h) * HIDD + d];
            }
            dst[e] = (_Float16)v;
        }
    } else if (blk == 588) {
        if (tid < NPAD) GW[tid] = (tid < HIDD) ? ln_g[tid] * W2[tid] : 0.f;
        if (tid == 0) {
            float sg = 0.f, sb = 0.f;
            for (int d = 0; d < HIDD; ++d) { sg += ln_g[d] * W2[d]; sb += ln_b[d] * W2[d]; }
            SCAL[0] = sg;
            SCAL[1] = sb + b2[0];
        }
    } else if (blk < 1165) {
        const bool isS = blk < 877;
        const int idx = (blk - (isS ? 589 : 877)) * 256 + tid;
        const float* Wsrc = isS ? W_start : W_end;
        _Float16* dstb = isS ? WSF : WEF;
        const int nt = idx / 1536;
        const int rem = idx - nt * 1536;
        const int kt = rem >> 6, lane = rem & 63;
        const int n = nt * 16 + (lane & 15);
        const int kb = kt * 32 + (lane >> 4) * 8;
        _Float16* dst = dstb + (size_t)idx * 8;
#pragma unroll
        for (int e = 0; e < 8; ++e) dst[e] = (_Float16)Wsrc[(size_t)(kb + e) * H + n];
    } else if (blk < 1741) {
        const int idx = (blk - 1165) * 256 + tid;
        const int nt = idx / 3072;
        const int rem = idx - nt * 3072;
        const int kt = rem >> 6, lane = rem & 63;
        const int n = nt * 16 + (lane & 15);
        const int kb = kt * 32 + (lane >> 4) * 8;
        _Float16* dst = WOF + (size_t)idx * 8;
#pragma unroll
        for (int e = 0; e < 8; ++e) dst[e] = (_Float16)W_out[(size_t)(kb + e) * H + n];
    } else {
        // zero-fill ant (65536 floats, 64 blocks)
        const int idx = (blk - 1741) * 256 + tid;
        *(float4*)(ant + (size_t)idx * 4) = make_float4(0.f, 0.f, 0.f, 0.f);
    }
}

// ============ kB: T table + av/cv (417 blocks) ============
__global__ __launch_bounds__(256) void kB(
    const float* __restrict__ biasP, const float* __restrict__ width_emb,
    const float* __restrict__ W_out, const float* __restrict__ W_start,
    const float* __restrict__ W_end, const float* __restrict__ WOV,
    float* __restrict__ T, float* __restrict__ av, float* __restrict__ cv) {
    const int blk = blockIdx.x, tid = threadIdx.x;
    if (blk < 33) {
        const int w = blk / 3, jb = blk - w * 3;
        const int j = jb * 256 + tid;
        float acc = 0.f;
#pragma unroll
        for (int kc = 0; kc < 8; ++kc) acc += biasP[kc * H + j];
#pragma unroll
        for (int k = 0; k < 30; ++k)
            acc += width_emb[w * 30 + k] * W_out[(size_t)(2 * H + k) * H + j];
        T[w * H + j] = acc;
    } else {
        const int wid = tid >> 6, lane = tid & 63;
        const int gr = (blk - 33) * 4 + wid;
        const float* row = (gr < H) ? (W_start + (size_t)gr * H) : (W_end + (size_t)(gr - H) * H);
        const float* vec = (gr < H) ? WOV : (WOV + H);
        float s = 0.f;
#pragma unroll
        for (int q = 0; q < 12; ++q) s += row[lane + 64 * q] * vec[lane + 64 * q];
#pragma unroll
        for (int off = 32; off; off >>= 1) s += __shfl_down(s, off, 64);
        if (lane == 0) {
            if (gr < H) av[gr] = s; else cv[gr - H] = s;
        }
    }
}

// position dots + tw
__global__ void k_posdots(const float* __restrict__ seq, const float* __restrict__ av,
                          const float* __restrict__ cv, const float* __restrict__ T,
                          const float* __restrict__ w_ment, const float* __restrict__ b_ment,
                          float* __restrict__ PD, float* __restrict__ tw) {
    const int wid = threadIdx.x >> 6, lane = threadIdx.x & 63;
    if (blockIdx.x < 2048) {
        const int r = blockIdx.x * 4 + wid;
        const float4* row = (const float4*)(seq + (size_t)r * H);
        const float4* a4 = (const float4*)av;
        const float4* c4 = (const float4*)cv;
        float sa = 0.f, sc = 0.f;
#pragma unroll
        for (int q = 0; q < 3; ++q) {
            float4 x = row[lane + 64 * q];
            float4 ya = a4[lane + 64 * q], yc = c4[lane + 64 * q];
            sa += x.x * ya.x + x.y * ya.y + x.z * ya.z + x.w * ya.w;
            sc += x.x * yc.x + x.y * yc.y + x.z * yc.z + x.w * yc.w;
        }
#pragma unroll
        for (int off = 32; off; off >>= 1) {
            sa += __shfl_down(sa, off, 64);
            sc += __shfl_down(sc, off, 64);
        }
        if (lane == 0) { PD[r] = sa; PD[8192 + r] = sc; }
    } else {
        for (int w = wid; w <= 10; w += 4) {
            float s = 0.f;
#pragma unroll
            for (int q = 0; q < 12; ++q) s += T[w * H + lane + 64 * q] * w_ment[lane + 64 * q];
#pragma unroll
            for (int off = 32; off; off >>= 1) s += __shfl_down(s, off, 64);
            if (lane == 0) tw[w] = s + b_ment[0];
        }
    }
}

// stage 1 sort (scores inline from PD)
__global__ __launch_bounds__(256) void k_sort1(const float* __restrict__ PD,
    const int* __restrict__ starts, const int* __restrict__ ends,
    const float* __restrict__ tw, unsigned long long* __restrict__ CAND) {
    __shared__ unsigned long long keys[512];
    const int blk = blockIdx.x;
    const int b = blk >> 3, c = blk & 7;
    const int tid = threadIdx.x;
    for (int i = tid; i < 512; i += 256) {
        const int gi = c * 512 + i;
        const int r = b * NSP + gi;
        const int s = starts[r], e = ends[r];
        int w = e - s; w = w < 0 ? 0 : (w > 10 ? 10 : w);
        const float sc = PD[b * SEQ + s] + PD[8192 + b * SEQ + e] + tw[w];
        unsigned u = __float_as_uint(sc);
        u = (u & 0x80000000u) ? ~u : (u | 0x80000000u);
        keys[i] = ((unsigned long long)u << 32) | (unsigned)(0xFFFFFFFFu - (unsigned)gi);
    }
    __syncthreads();
    for (int k = 2; k <= 512; k <<= 1) {
        for (int j = k >> 1; j > 0; j >>= 1) {
            const int p = tid;
            const int i = ((p & ~(j - 1)) << 1) | (p & (j - 1));
            const int l = i | j;
            unsigned long long a = keys[i], d = keys[l];
            const bool desc = ((i & k) == 0);
            if ((a < d) == desc) { keys[i] = d; keys[l] = a; }
            __syncthreads();
        }
    }
    if (tid < 128) CAND[(size_t)(b * 8 + c) * 128 + tid] = keys[tid];
}

// stage 2: bitonic top-k merge of 8 sorted-desc 128-lists
__global__ __launch_bounds__(256) void k_sort2(const unsigned long long* __restrict__ CAND,
    const int* __restrict__ starts, const int* __restrict__ ends,
    float* __restrict__ out, int* __restrict__ fsI, int* __restrict__ feI,
    int* __restrict__ widI) {
    __shared__ unsigned long long K[1024];
    const int b = blockIdx.x, tid = threadIdx.x;
    for (int i = tid; i < 1024; i += 256) K[i] = CAND[(size_t)b * 1024 + i];
    __syncthreads();
    for (int nl = 4; nl >= 1; nl >>= 1) {
        const int items = nl * 128;
        unsigned long long v0 = 0, v1 = 0;
        if (tid < items) {
            const int q = tid >> 7, r = tid & 127;
            unsigned long long a = K[q * 256 + r];
            unsigned long long d = K[q * 256 + 128 + (127 - r)];
            v0 = a > d ? a : d;
        }
        if (tid + 256 < items) {
            const int i = tid + 256;
            const int q = i >> 7, r = i & 127;
            unsigned long long a = K[q * 256 + r];
            unsigned long long d = K[q * 256 + 128 + (127 - r)];
            v1 = a > d ? a : d;
        }
        __syncthreads();
        if (tid < items) K[(tid >> 7) * 128 + (tid & 127)] = v0;
        if (tid + 256 < items) { const int i = tid + 256; K[(i >> 7) * 128 + (i & 127)] = v1; }
        __syncthreads();
        for (int j = 64; j; j >>= 1) {
            const int pairs = nl * 64;
            for (int i = tid; i < pairs; i += 256) {
                const int q = i >> 6, r = i & 63;
                const int lo = q * 128 + (((r & ~(j - 1)) << 1) | (r & (j - 1)));
                const int hi = lo + j;
                unsigned long long a = K[lo], d = K[hi];
                if (a < d) { K[lo] = d; K[hi] = a; }
            }
            __syncthreads();
        }
    }
    if (tid < TOPK) {
        const unsigned long long key = K[tid];
        const int widx = (int)(0xFFFFFFFFu - (unsigned)(key & 0xFFFFFFFFu));
        const unsigned hu = (unsigned)(key >> 32);
        const float sval = __uint_as_float((hu & 0x80000000u) ? (hu & 0x7FFFFFFFu) : ~hu);
        const int s = starts[b * NSP + widx], e = ends[b * NSP + widx];
        const int p = b * TOPK + tid;
        out[p] = sval;
        out[OFS_FS + p] = (float)s;
        out[OFS_FE + p] = (float)e;
        fsI[p] = b * SEQ + s;
        feI[p] = b * SEQ + e;
        int w = e - s;
        widI[p] = w < 0 ? 0 : (w > 10 ? 10 : w);
    }
}

// SEH(1024x768) = gathered-seq @ [W_start | W_end], fused gather + cvt, reg-pipelined.
__global__ __launch_bounds__(256) void k_gemm1(const float* __restrict__ seq,
    const int* __restrict__ fsI, const int* __restrict__ feI,
    const _Float16* __restrict__ WSF, const _Float16* __restrict__ WEF,
    _Float16* __restrict__ SEH) {
    const int mt = blockIdx.x;
    const int wave = threadIdx.x >> 6, lane = threadIdx.x & 63;
    const int g = lane >> 4;
    const int nt0 = blockIdx.y * 8 + wave * 2;
    const int gi = mt * 16 + (lane & 15);
    const int src = (mt < 32) ? fsI[gi] : feI[gi - 512];
    const float* Arow = seq + (size_t)src * H + g * 8;
    const _Float16* BF = (mt < 32) ? WSF : WEF;
    f32x4 acc0 = {0.f, 0.f, 0.f, 0.f}, acc1 = acc0;
    float4 v0 = *(const float4*)(Arow);
    float4 v1 = *(const float4*)(Arow + 4);
    half8 b0 = *(const half8*)(BF + ((size_t)(nt0 * 24) * 64 + lane) * 8);
    half8 b1 = *(const half8*)(BF + ((size_t)((nt0 + 1) * 24) * 64 + lane) * 8);
    for (int kt = 0; kt < 24; ++kt) {
        float4 nv0, nv1;
        half8 nb0, nb1;
        if (kt < 23) {
            nv0 = *(const float4*)(Arow + (kt + 1) * 32);
            nv1 = *(const float4*)(Arow + (kt + 1) * 32 + 4);
            nb0 = *(const half8*)(BF + ((size_t)(nt0 * 24 + kt + 1) * 64 + lane) * 8);
            nb1 = *(const half8*)(BF + ((size_t)((nt0 + 1) * 24 + kt + 1) * 64 + lane) * 8);
        }
        half8 a = {(_Float16)v0.x, (_Float16)v0.y, (_Float16)v0.z, (_Float16)v0.w,
                   (_Float16)v1.x, (_Float16)v1.y, (_Float16)v1.z, (_Float16)v1.w};
        acc0 = __builtin_amdgcn_mfma_f32_16x16x32_f16(a, b0, acc0, 0, 0, 0);
        acc1 = __builtin_amdgcn_mfma_f32_16x16x32_f16(a, b1, acc1, 0, 0, 0);
        if (kt < 23) { v0 = nv0; v1 = nv1; b0 = nb0; b1 = nb1; }
    }
    const int c = lane & 15, quad = lane >> 4;
#pragma unroll
    for (int r = 0; r < 4; ++r) {
        const int row = mt * 16 + quad * 4 + r;
        SEH[(size_t)row * H + nt0 * 16 + c] = (_Float16)acc0[r];
        SEH[(size_t)row * H + (nt0 + 1) * 16 + c] = (_Float16)acc1[r];
    }
}

// RKP2[kh] = SEH-half @ W_out-half via f16 MFMA, reg-pipelined. grid (32, 6, 2)
__global__ __launch_bounds__(256) void k_gemm2(const _Float16* __restrict__ SEH,
    const _Float16* __restrict__ WOF, float* __restrict__ RKP2) {
    const int mt = blockIdx.x, kh = blockIdx.z;
    const int wave = threadIdx.x >> 6, lane = threadIdx.x & 63;
    const int nt0 = blockIdx.y * 8 + wave * 2;
    const _Float16* Arow = SEH + (size_t)(kh * 512 + mt * 16 + (lane & 15)) * H + (lane >> 4) * 8;
    const _Float16* B0 = WOF + ((size_t)(nt0 * 48 + kh * 24) * 64 + lane) * 8;
    const _Float16* B1 = WOF + ((size_t)((nt0 + 1) * 48 + kh * 24) * 64 + lane) * 8;
    f32x4 acc0 = {0.f, 0.f, 0.f, 0.f}, acc1 = acc0;
    half8 a = *(const half8*)(Arow);
    half8 b0 = *(const half8*)(B0);
    half8 b1 = *(const half8*)(B1);
    for (int kt2 = 0; kt2 < 24; ++kt2) {
        half8 na, nb0, nb1;
        if (kt2 < 23) {
            na = *(const half8*)(Arow + (kt2 + 1) * 32);
            nb0 = *(const half8*)(B0 + (size_t)(kt2 + 1) * 512);
            nb1 = *(const half8*)(B1 + (size_t)(kt2 + 1) * 512);
        }
        acc0 = __builtin_amdgcn_mfma_f32_16x16x32_f16(a, b0, acc0, 0, 0, 0);
        acc1 = __builtin_amdgcn_mfma_f32_16x16x32_f16(a, b1, acc1, 0, 0, 0);
        if (kt2 < 23) { a = na; b0 = nb0; b1 = nb1; }
    }
    const int c = lane & 15, quad = lane >> 4;
    float* dst = RKP2 + (size_t)kh * 512 * H;
#pragma unroll
    for (int r = 0; r < 4; ++r) {
        const int row = mt * 16 + quad * 4 + r;
        dst[(size_t)row * H + nt0 * 16 + c] = acc0[r];
        dst[(size_t)row * H + (nt0 + 1) * 16 + c] = acc1[r];
    }
}

// RKH[p] = (f16)(RKP2[0][p] + RKP2[1][p] + T[wid[p]])
__global__ void k_fin(const float* __restrict__ RKP2, const float* __restrict__ T,
                      const int* __restrict__ widI, _Float16* __restrict__ RKH) {
    const int p = blockIdx.x, tid = threadIdx.x;
    if (tid >= 192) return;
    const int w = widI[p];
    const int c0 = tid * 4;
    float4 s = *(const float4*)(T + (size_t)w * H + c0);
    float4 v0 = *(const float4*)(RKP2 + (size_t)p * H + c0);
    float4 v1 = *(const float4*)(RKP2 + (size_t)(512 + p) * H + c0);
    half4 h = {(_Float16)(s.x + v0.x + v1.x), (_Float16)(s.y + v0.y + v1.y),
               (_Float16)(s.z + v0.z + v1.z), (_Float16)(s.w + v0.w + v1.w)};
    *(half4*)(RKH + (size_t)p * H + c0) = h;
}

// U/V partials via f16 MFMA (A from RKH rows), K-split x2, reg-pipelined
__global__ __launch_bounds__(256) void k_uv3(const _Float16* __restrict__ RKH,
    const _Float16* __restrict__ WCF, float* __restrict__ UVP) {
    const int t = blockIdx.x, kh = blockIdx.y;
    const int wave = threadIdx.x >> 6, lane = threadIdx.x & 63;
    const _Float16* Arow = RKH + (size_t)(t * 16 + (lane & 15)) * H + (lane >> 4) * 8 + kh * 384;
    f32x4 acc[5];
#pragma unroll
    for (int q = 0; q < 5; ++q) acc[q] = (f32x4){0.f, 0.f, 0.f, 0.f};
    half8 a = *(const half8*)(Arow);
    half8 bv[5], nbv[5];
#pragma unroll
    for (int q = 0; q < 5; ++q)
        bv[q] = *(const half8*)(WCF + ((size_t)(((wave * 5 + q) * 24 + kh * 12) * 64 + lane)) * 8);
    for (int kk = 0; kk < 12; ++kk) {
        half8 na;
        if (kk < 11) {
            const int kt = kh * 12 + kk + 1;
            na = *(const half8*)(Arow + (kk + 1) * 32);
#pragma unroll
            for (int q = 0; q < 5; ++q)
                nbv[q] = *(const half8*)(WCF + ((size_t)(((wave * 5 + q) * 24 + kt) * 64 + lane)) * 8);
        }
#pragma unroll
        for (int q = 0; q < 5; ++q)
            acc[q] = __builtin_amdgcn_mfma_f32_16x16x32_f16(a, bv[q], acc[q], 0, 0, 0);
        if (kk < 11) {
            a = na;
#pragma unroll
            for (int q = 0; q < 5; ++q) bv[q] = nbv[q];
        }
    }
    const int c = lane & 15, g = lane >> 4;
#pragma unroll
    for (int q = 0; q < 5; ++q) {
        const int n = (wave * 5 + q) * 16 + c;
#pragma unroll
        for (int r = 0; r < 4; ++r) {
            const int p = t * 16 + g * 4 + r;
            UVP[((size_t)kh * 512 + p) * 320 + n] = acc[q][r];
        }
    }
}

// Pairwise MFMA v6: 16i x 16j triangular tile (36 pairs x 4 b); wave owns 4 i's
// sharing bv[10] + rj; no LDS/barriers; register double-buffer pipeline.
__global__ __launch_bounds__(256, 1) void k_pair(
    const _Float16* __restrict__ WF, const _Float16* __restrict__ RKH,
    const float* __restrict__ UVP, const float* __restrict__ b1,
    const float* __restrict__ GW, const float* __restrict__ SCAL,
    float* __restrict__ ant) {
    const int b = blockIdx.y;
    int ti = 0, rem = blockIdx.x;
    while (rem >= ti + 1) { rem -= ti + 1; ++ti; }
    const int tj = rem;
    const int wave = threadIdx.x >> 6, lane = threadIdx.x & 63;
    const int g = lane >> 4, c = lane & 15;
    const int i0 = ti * 16 + wave * 4;
    const int j0 = tj * 16;

    const _Float16* Rj = RKH + (size_t)(b * TOPK + j0 + c) * H + g * 8;
    const _Float16* Ri0 = RKH + (size_t)(b * TOPK + i0) * H + g * 8;
    const _Float16* Ri1 = Ri0 + H;
    const _Float16* Ri2 = Ri1 + H;
    const _Float16* Ri3 = Ri2 + H;
    const _Float16* Wl = WF + (size_t)lane * 8;

    f32x4 acc[4][10];
#pragma unroll
    for (int q = 0; q < 4; ++q)
#pragma unroll
        for (int nt = 0; nt < 10; ++nt) acc[q][nt] = (f32x4){0.f, 0.f, 0.f, 0.f};

    half8 bv[10], nbv[10];
    half8 rj, nrj, ri0, ri1, ri2, ri3, nri0, nri1, nri2, nri3;
#pragma unroll
    for (int nt = 0; nt < 10; ++nt) bv[nt] = *(const half8*)(Wl + (size_t)nt * 512);
    rj  = *(const half8*)(Rj);
    ri0 = *(const half8*)(Ri0);
    ri1 = *(const half8*)(Ri1);
    ri2 = *(const half8*)(Ri2);
    ri3 = *(const half8*)(Ri3);

    for (int kt = 0; kt < 24; ++kt) {
        if (kt < 23) {
            const _Float16* wsrc = Wl + (size_t)(kt + 1) * 5120;
#pragma unroll
            for (int nt = 0; nt < 10; ++nt) nbv[nt] = *(const half8*)(wsrc + (size_t)nt * 512);
            nrj  = *(const half8*)(Rj + (kt + 1) * 32);
            nri0 = *(const half8*)(Ri0 + (kt + 1) * 32);
            nri1 = *(const half8*)(Ri1 + (kt + 1) * 32);
            nri2 = *(const half8*)(Ri2 + (kt + 1) * 32);
            nri3 = *(const half8*)(Ri3 + (kt + 1) * 32);
        }
        half8 a0 = ri0 * rj;
        half8 a1 = ri1 * rj;
        half8 a2 = ri2 * rj;
        half8 a3 = ri3 * rj;
#pragma unroll
        for (int nt = 0; nt < 10; ++nt) {
            acc[0][nt] = __builtin_amdgcn_mfma_f32_16x16x32_f16(a0, bv[nt], acc[0][nt], 0, 0, 0);
            acc[1][nt] = __builtin_amdgcn_mfma_f32_16x16x32_f16(a1, bv[nt], acc[1][nt], 0, 0, 0);
            acc[2][nt] = __builtin_amdgcn_mfma_f32_16x16x32_f16(a2, bv[nt], acc[2][nt], 0, 0, 0);
            acc[3][nt] = __builtin_amdgcn_mfma_f32_16x16x32_f16(a3, bv[nt], acc[3][nt], 0, 0, 0);
        }
        if (kt < 23) {
#pragma unroll
            for (int nt = 0; nt < 10; ++nt) bv[nt] = nbv[nt];
            rj = nrj; ri0 = nri0; ri1 = nri1; ri2 = nri2; ri3 = nri3;
        }
    }

    const float Sgw = SCAL[0], C0 = SCAL[1];
    float gw10[10];
#pragma unroll
    for (int nt = 0; nt < 10; ++nt) gw10[nt] = GW[nt * 16 + c];

#pragma unroll
    for (int q = 0; q < 4; ++q) {
        const int i = i0 + q;
        const int pi = b * TOPK + i;
        float u10[10];
#pragma unroll
        for (int nt = 0; nt < 10; ++nt) {
            const int d = nt * 16 + c;
            const float ub = (d < HIDD) ? b1[d] : 0.f;
            u10[nt] = UVP[(size_t)pi * 320 + d] + UVP[(size_t)(512 + pi) * 320 + d] + ub;
        }
#pragma unroll
        for (int r = 0; r < 4; ++r) {
            const int j = j0 + g * 4 + r;
            const int pj = b * TOPK + j;
            const float* Vp0 = UVP + (size_t)pj * 320 + 160;
            const float* Vp1 = UVP + (size_t)(512 + pj) * 320 + 160;
            float s1 = 0.f, s2 = 0.f, s3 = 0.f;
#pragma unroll
            for (int nt = 0; nt < 10; ++nt) {
                const int d = nt * 16 + c;
                float z = acc[q][nt][r] + u10[nt] + Vp0[d] + Vp1[d];
                float h = (d < HIDD && z > 0.f) ? z : 0.f;
                s1 += h;
                s2 += h * h;
                s3 += h * gw10[nt];
            }
#pragma unroll
            for (int off = 1; off < 16; off <<= 1) {
                s1 += __shfl_xor(s1, off, 64);
                s2 += __shfl_xor(s2, off, 64);
                s3 += __shfl_xor(s3, off, 64);
            }
            const float mu = s1 * (1.f / HIDD);
            const float var = s2 * (1.f / HIDD) - mu * mu;
            const float rstd = rsqrtf(var + 1e-5f);
            const float val = rstd * (s3 - mu * Sgw) + C0;
            if (c == 0 && j < i) ant[((size_t)b * TOPK + i) * TOPK + j] = val;
        }
    }
}

extern "C" void kernel_launch(void* const* d_in, const int* in_sizes, int n_in,
                              void* d_out, int out_size, void* d_ws, size_t ws_size,
                              hipStream_t stream) {
    const float* seq      = (const float*)d_in[0];
    const int*   starts   = (const int*)d_in[1];
    const int*   ends     = (const int*)d_in[2];
    const float* W_start  = (const float*)d_in[3];
    const float* b_start  = (const float*)d_in[4];
    const float* W_end    = (const float*)d_in[5];
    const float* b_end    = (const float*)d_in[6];
    const float* width_e  = (const float*)d_in[7];
    const float* W_out    = (const float*)d_in[8];
    const float* b_out    = (const float*)d_in[9];
    const float* w_ment   = (const float*)d_in[10];
    const float* b_ment   = (const float*)d_in[11];
    const float* W1       = (const float*)d_in[12];
    const float* b1       = (const float*)d_in[13];
    const float* ln_g     = (const float*)d_in[14];
    const float* ln_b     = (const float*)d_in[15];
    const float* W2       = (const float*)d_in[16];
    const float* b2       = (const float*)d_in[17];
    float* out = (float*)d_out;
    float* ws  = (float*)d_ws;

    float* Tt    = ws + OFF_T;
    float* biasP = ws + OFF_BIASP;
    float* WOV   = ws + OFF_WOV;
    float* av    = ws + OFF_AV;
    float* cv    = ws + OFF_CV;
    float* tw    = ws + OFF_TW;
    float* PD    = ws + OFF_PD;
    unsigned long long* CANDp = (unsigned long long*)(ws + OFF_CAND);
    int*   fsI   = (int*)(ws + OFF_FS);
    int*   feI   = (int*)(ws + OFF_FE);
    int*   widI  = (int*)(ws + OFF_WID);
    float* UVPp  = ws + OFF_UVP;
    float* GWp   = ws + OFF_GW;
    float* SCALp = ws + OFF_SCAL;
    _Float16* WFp   = (_Float16*)(ws + OFF_WF);
    _Float16* WCFp  = (_Float16*)(ws + OFF_WCF);
    _Float16* WSFp  = (_Float16*)(ws + OFF_WSF);
    _Float16* WEFp  = (_Float16*)(ws + OFF_WEF);
    _Float16* WOFp  = (_Float16*)(ws + OFF_WOF);
    _Float16* SEHp  = (_Float16*)(ws + OFF_SEH);
    _Float16* RKHp  = (_Float16*)(ws + OFF_RKH);
    float* RKP2p = ws + OFF_RKP2;

    kA<<<1805, 256, 0, stream>>>(b_start, b_end, b_out, W_out, w_ment, W1,
                                 ln_g, ln_b, W2, b2, W_start, W_end,
                                 biasP, WOV, WFp, WCFp, WSFp, WEFp, WOFp, GWp, SCALp,
                                 out + OFS_ANT);
    kB<<<417, 256, 0, stream>>>(biasP, width_e, W_out, W_start, W_end, WOV, Tt, av, cv);
    k_posdots<<<2049, 256, 0, stream>>>(seq, av, cv, Tt, w_ment, b_ment, PD, tw);
    k_sort1<<<32, 256, 0, stream>>>(PD, starts, ends, tw, CANDp);
    k_sort2<<<4, 256, 0, stream>>>(CANDp, starts, ends, out, fsI, feI, widI);
    k_gemm1<<<dim3(64, 6), 256, 0, stream>>>(seq, fsI, feI, WSFp, WEFp, SEHp);
    k_gemm2<<<dim3(32, 6, 2), 256, 0, stream>>>(SEHp, WOFp, RKP2p);
    k_fin<<<512, 192, 0, stream>>>(RKP2p, Tt, widI, RKHp);
    k_uv3<<<dim3(32, 2), 256, 0, stream>>>(RKHp, WCFp, UVPp);
    k_pair<<<dim3(36, 4), 256, 0, stream>>>(WFp, RKHp, UVPp, b1, GWp, SCALp,
                                            out + OFS_ANT);
}

// Round 14
// 198.895 us; speedup vs baseline: 1.0993x; 1.0094x over previous
//
#include <hip/hip_runtime.h>
#include <math.h>

#define H 768
#define SEQ 2048
#define NSP 4096
#define HIDD 150
#define TOPK 128
#define NPAD 160

// d_out layout (floats): [0,512) mention_scores | [512,66048) ant | [66048,66560) f_starts | [66560,67072) f_ends
#define OFS_ANT 512
#define OFS_FS 66048
#define OFS_FE 66560

// workspace layout (float offsets)
static const size_t OFF_T     = 0ull;         // 11*768
static const size_t OFF_BIASP = 8448ull;      // 8*768
static const size_t OFF_WOV   = 14592ull;     // 1536
static const size_t OFF_AV    = 16128ull;     // 768
static const size_t OFF_CV    = 16896ull;     // 768
static const size_t OFF_TW    = 17664ull;     // 16
static const size_t OFF_PD    = 17680ull;     // 2*8192
static const size_t OFF_CAND  = 34064ull;     // 4096 u64 = 8192 f32 (even -> 8B aligned)
static const size_t OFF_FS    = 42256ull;     // 512 ints
static const size_t OFF_FE    = 42768ull;     // 512 ints
static const size_t OFF_WID   = 43280ull;     // 512 ints
static const size_t OFF_UVP   = 43792ull;     // 2*512*320 f32
static const size_t OFF_GW    = 371472ull;    // 160
static const size_t OFF_SCAL  = 371632ull;    // 8
static const size_t OFF_WF    = 371640ull;    // 61440   (Wd f16 frags, kt-major: [24kt][10nt][64][8])
static const size_t OFF_WCF   = 433080ull;    // 122880  (UV f16 B-frags, [20nt][24kt][64][8])
static const size_t OFF_WSF   = 555960ull;    // 294912  (W_start f16 B-frags, 48nt x 24kt)
static const size_t OFF_WEF   = 850872ull;    // 294912  (W_end   f16 B-frags)
static const size_t OFF_WOF   = 1145784ull;   // 589824  (W_out   f16 B-frags, 48nt x 48kt)
static const size_t OFF_SEH   = 1735608ull;   // 1024*768 f16 = 393216 f32
static const size_t OFF_RKH   = 2128824ull;   // 512*768 f16 = 196608 f32 (row-major repr_k)
static const size_t OFF_RKP2  = 2325432ull;   // 2*512*768 f32 partials

typedef __attribute__((ext_vector_type(8))) _Float16 half8;
typedef __attribute__((ext_vector_type(4))) _Float16 half4;
typedef __attribute__((ext_vector_type(4))) float f32x4;

// ============ kA: independent preps (1805 blocks) ============
__global__ __launch_bounds__(256) void kA(
    const float* __restrict__ b_start, const float* __restrict__ b_end,
    const float* __restrict__ b_out, const float* __restrict__ W_out,
    const float* __restrict__ w_ment, const float* __restrict__ W1,
    const float* __restrict__ ln_g, const float* __restrict__ ln_b,
    const float* __restrict__ W2, const float* __restrict__ b2,
    const float* __restrict__ W_start, const float* __restrict__ W_end,
    float* __restrict__ biasP, float* __restrict__ WOV,
    _Float16* __restrict__ WF, _Float16* __restrict__ WCF,
    _Float16* __restrict__ WSF, _Float16* __restrict__ WEF,
    _Float16* __restrict__ WOF, float* __restrict__ GW, float* __restrict__ SCAL,
    float* __restrict__ ant) {
    const int blk = blockIdx.x, tid = threadIdx.x;
    if (blk < 24) {
        const int kc = blk / 3, jb = blk - kc * 3;
        const int j = jb * 256 + tid;
        float acc = (kc == 0) ? b_out[j] : 0.f;
        const int k0 = kc * 96;
#pragma unroll 4
        for (int k = k0; k < k0 + 96; ++k) {
            acc += b_start[k] * W_out[(size_t)k * H + j];
            acc += b_end[k]   * W_out[(size_t)(H + k) * H + j];
        }
        biasP[kc * H + j] = acc;
    } else if (blk < 408) {
        const int wid = tid >> 6, lane = tid & 63;
        const int gr = (blk - 24) * 4 + wid;
        const float* row = W_out + (size_t)gr * H;
        float s = 0.f;
#pragma unroll
        for (int q = 0; q < 12; ++q) s += row[lane + 64 * q] * w_ment[lane + 64 * q];
#pragma unroll
        for (int off = 32; off; off >>= 1) s += __shfl_down(s, off, 64);
        if (lane == 0) WOV[gr] = s;
    } else if (blk < 468) {
        // WF: kt-major layout [kt][nt][lane][8]
        const int idx = (blk - 408) * 256 + tid;
        const int nt = idx / 1536;
        const int rem = idx - nt * 1536;
        const int kt = rem >> 6, lane = rem & 63;
        const int n = nt * 16 + (lane & 15);
        const int kb = kt * 32 + (lane >> 4) * 8;
        _Float16* dst = WF + ((size_t)((kt * 10 + nt) * 64 + lane)) * 8;
#pragma unroll
        for (int e = 0; e < 8; ++e) {
            float v = (n < HIDD) ? W1[(size_t)(3 * H + kb + e) * HIDD + n] : 0.f;
            dst[e] = (_Float16)v;
        }
    } else if (blk < 588) {
        const int idx = (blk - 468) * 256 + tid;
        const int nt = idx / 1536;
        const int rem = idx - nt * 1536;
        const int kt = rem >> 6, lane = rem & 63;
        const int n = nt * 16 + (lane & 15);
        const int kb = kt * 32 + (lane >> 4) * 8;
        _Float16* dst = WCF + (size_t)idx * 8;
#pragma unroll
        for (int e = 0; e < 8; ++e) {
            const int h = kb + e;
            float v = 0.f;
            if (n < 160) {
                if (n < HIDD)
                    v = W1[(size_t)h * HIDD + n] + W1[(size_t)(2 * H + h) * HIDD + n];
            } else {
                const int d = n - 160;
                if (d < HIDD)
                    v = W1[(size_t)(H + h) * HIDD + d] - W1[(size_t)(2 * H + h) * HIDD + d];
            }
            dst[e] = (_Float16)v;
        }
    } else if (blk == 588) {
        if (tid < NPAD) GW[tid] = (tid < HIDD) ? ln_g[tid] * W2[tid] : 0.f;
        if (tid == 0) {
            float sg = 0.f, sb = 0.f;
            for (int d = 0; d < HIDD; ++d) { sg += ln_g[d] * W2[d]; sb += ln_b[d] * W2[d]; }
            SCAL[0] = sg;
            SCAL[1] = sb + b2[0];
        }
    } else if (blk < 1165) {
        const bool isS = blk < 877;
        const int idx = (blk - (isS ? 589 : 877)) * 256 + tid;
        const float* Wsrc = isS ? W_start : W_end;
        _Float16* dstb = isS ? WSF : WEF;
        const int nt = idx / 1536;
        const int rem = idx - nt * 1536;
        const int kt = rem >> 6, lane = rem & 63;
        const int n = nt * 16 + (lane & 15);
        const int kb = kt * 32 + (lane >> 4) * 8;
        _Float16* dst = dstb + (size_t)idx * 8;
#pragma unroll
        for (int e = 0; e < 8; ++e) dst[e] = (_Float16)Wsrc[(size_t)(kb + e) * H + n];
    } else if (blk < 1741) {
        const int idx = (blk - 1165) * 256 + tid;
        const int nt = idx / 3072;
        const int rem = idx - nt * 3072;
        const int kt = rem >> 6, lane = rem & 63;
        const int n = nt * 16 + (lane & 15);
        const int kb = kt * 32 + (lane >> 4) * 8;
        _Float16* dst = WOF + (size_t)idx * 8;
#pragma unroll
        for (int e = 0; e < 8; ++e) dst[e] = (_Float16)W_out[(size_t)(kb + e) * H + n];
    } else {
        // zero-fill ant (65536 floats, 64 blocks)
        const int idx = (blk - 1741) * 256 + tid;
        *(float4*)(ant + (size_t)idx * 4) = make_float4(0.f, 0.f, 0.f, 0.f);
    }
}

// ============ kB: T table + av/cv (417 blocks) ============
__global__ __launch_bounds__(256) void kB(
    const float* __restrict__ biasP, const float* __restrict__ width_emb,
    const float* __restrict__ W_out, const float* __restrict__ W_start,
    const float* __restrict__ W_end, const float* __restrict__ WOV,
    float* __restrict__ T, float* __restrict__ av, float* __restrict__ cv) {
    const int blk = blockIdx.x, tid = threadIdx.x;
    if (blk < 33) {
        const int w = blk / 3, jb = blk - w * 3;
        const int j = jb * 256 + tid;
        float acc = 0.f;
#pragma unroll
        for (int kc = 0; kc < 8; ++kc) acc += biasP[kc * H + j];
#pragma unroll
        for (int k = 0; k < 30; ++k)
            acc += width_emb[w * 30 + k] * W_out[(size_t)(2 * H + k) * H + j];
        T[w * H + j] = acc;
    } else {
        const int wid = tid >> 6, lane = tid & 63;
        const int gr = (blk - 33) * 4 + wid;
        const float* row = (gr < H) ? (W_start + (size_t)gr * H) : (W_end + (size_t)(gr - H) * H);
        const float* vec = (gr < H) ? WOV : (WOV + H);
        float s = 0.f;
#pragma unroll
        for (int q = 0; q < 12; ++q) s += row[lane + 64 * q] * vec[lane + 64 * q];
#pragma unroll
        for (int off = 32; off; off >>= 1) s += __shfl_down(s, off, 64);
        if (lane == 0) {
            if (gr < H) av[gr] = s; else cv[gr - H] = s;
        }
    }
}

// position dots + tw
__global__ void k_posdots(const float* __restrict__ seq, const float* __restrict__ av,
                          const float* __restrict__ cv, const float* __restrict__ T,
                          const float* __restrict__ w_ment, const float* __restrict__ b_ment,
                          float* __restrict__ PD, float* __restrict__ tw) {
    const int wid = threadIdx.x >> 6, lane = threadIdx.x & 63;
    if (blockIdx.x < 2048) {
        const int r = blockIdx.x * 4 + wid;
        const float4* row = (const float4*)(seq + (size_t)r * H);
        const float4* a4 = (const float4*)av;
        const float4* c4 = (const float4*)cv;
        float sa = 0.f, sc = 0.f;
#pragma unroll
        for (int q = 0; q < 3; ++q) {
            float4 x = row[lane + 64 * q];
            float4 ya = a4[lane + 64 * q], yc = c4[lane + 64 * q];
            sa += x.x * ya.x + x.y * ya.y + x.z * ya.z + x.w * ya.w;
            sc += x.x * yc.x + x.y * yc.y + x.z * yc.z + x.w * yc.w;
        }
#pragma unroll
        for (int off = 32; off; off >>= 1) {
            sa += __shfl_down(sa, off, 64);
            sc += __shfl_down(sc, off, 64);
        }
        if (lane == 0) { PD[r] = sa; PD[8192 + r] = sc; }
    } else {
        for (int w = wid; w <= 10; w += 4) {
            float s = 0.f;
#pragma unroll
            for (int q = 0; q < 12; ++q) s += T[w * H + lane + 64 * q] * w_ment[lane + 64 * q];
#pragma unroll
            for (int off = 32; off; off >>= 1) s += __shfl_down(s, off, 64);
            if (lane == 0) tw[w] = s + b_ment[0];
        }
    }
}

// stage 1 sort (scores inline from PD)
__global__ __launch_bounds__(256) void k_sort1(const float* __restrict__ PD,
    const int* __restrict__ starts, const int* __restrict__ ends,
    const float* __restrict__ tw, unsigned long long* __restrict__ CAND) {
    __shared__ unsigned long long keys[512];
    const int blk = blockIdx.x;
    const int b = blk >> 3, c = blk & 7;
    const int tid = threadIdx.x;
    for (int i = tid; i < 512; i += 256) {
        const int gi = c * 512 + i;
        const int r = b * NSP + gi;
        const int s = starts[r], e = ends[r];
        int w = e - s; w = w < 0 ? 0 : (w > 10 ? 10 : w);
        const float sc = PD[b * SEQ + s] + PD[8192 + b * SEQ + e] + tw[w];
        unsigned u = __float_as_uint(sc);
        u = (u & 0x80000000u) ? ~u : (u | 0x80000000u);
        keys[i] = ((unsigned long long)u << 32) | (unsigned)(0xFFFFFFFFu - (unsigned)gi);
    }
    __syncthreads();
    for (int k = 2; k <= 512; k <<= 1) {
        for (int j = k >> 1; j > 0; j >>= 1) {
            const int p = tid;
            const int i = ((p & ~(j - 1)) << 1) | (p & (j - 1));
            const int l = i | j;
            unsigned long long a = keys[i], d = keys[l];
            const bool desc = ((i & k) == 0);
            if ((a < d) == desc) { keys[i] = d; keys[l] = a; }
            __syncthreads();
        }
    }
    if (tid < 128) CAND[(size_t)(b * 8 + c) * 128 + tid] = keys[tid];
}

// stage 2: bitonic top-k merge of 8 sorted-desc 128-lists
__global__ __launch_bounds__(256) void k_sort2(const unsigned long long* __restrict__ CAND,
    const int* __restrict__ starts, const int* __restrict__ ends,
    float* __restrict__ out, int* __restrict__ fsI, int* __restrict__ feI,
    int* __restrict__ widI) {
    __shared__ unsigned long long K[1024];
    const int b = blockIdx.x, tid = threadIdx.x;
    for (int i = tid; i < 1024; i += 256) K[i] = CAND[(size_t)b * 1024 + i];
    __syncthreads();
    for (int nl = 4; nl >= 1; nl >>= 1) {
        const int items = nl * 128;
        unsigned long long v0 = 0, v1 = 0;
        if (tid < items) {
            const int q = tid >> 7, r = tid & 127;
            unsigned long long a = K[q * 256 + r];
            unsigned long long d = K[q * 256 + 128 + (127 - r)];
            v0 = a > d ? a : d;
        }
        if (tid + 256 < items) {
            const int i = tid + 256;
            const int q = i >> 7, r = i & 127;
            unsigned long long a = K[q * 256 + r];
            unsigned long long d = K[q * 256 + 128 + (127 - r)];
            v1 = a > d ? a : d;
        }
        __syncthreads();
        if (tid < items) K[(tid >> 7) * 128 + (tid & 127)] = v0;
        if (tid + 256 < items) { const int i = tid + 256; K[(i >> 7) * 128 + (i & 127)] = v1; }
        __syncthreads();
        for (int j = 64; j; j >>= 1) {
            const int pairs = nl * 64;
            for (int i = tid; i < pairs; i += 256) {
                const int q = i >> 6, r = i & 63;
                const int lo = q * 128 + (((r & ~(j - 1)) << 1) | (r & (j - 1)));
                const int hi = lo + j;
                unsigned long long a = K[lo], d = K[hi];
                if (a < d) { K[lo] = d; K[hi] = a; }
            }
            __syncthreads();
        }
    }
    if (tid < TOPK) {
        const unsigned long long key = K[tid];
        const int widx = (int)(0xFFFFFFFFu - (unsigned)(key & 0xFFFFFFFFu));
        const unsigned hu = (unsigned)(key >> 32);
        const float sval = __uint_as_float((hu & 0x80000000u) ? (hu & 0x7FFFFFFFu) : ~hu);
        const int s = starts[b * NSP + widx], e = ends[b * NSP + widx];
        const int p = b * TOPK + tid;
        out[p] = sval;
        out[OFS_FS + p] = (float)s;
        out[OFS_FE + p] = (float)e;
        fsI[p] = b * SEQ + s;
        feI[p] = b * SEQ + e;
        int w = e - s;
        widI[p] = w < 0 ? 0 : (w > 10 ? 10 : w);
    }
}

// SEH(1024x768) = gathered-seq @ [W_start | W_end], fused gather + cvt, reg-pipelined.
__global__ __launch_bounds__(256) void k_gemm1(const float* __restrict__ seq,
    const int* __restrict__ fsI, const int* __restrict__ feI,
    const _Float16* __restrict__ WSF, const _Float16* __restrict__ WEF,
    _Float16* __restrict__ SEH) {
    const int mt = blockIdx.x;
    const int wave = threadIdx.x >> 6, lane = threadIdx.x & 63;
    const int g = lane >> 4;
    const int nt0 = blockIdx.y * 8 + wave * 2;
    const int gi = mt * 16 + (lane & 15);
    const int src = (mt < 32) ? fsI[gi] : feI[gi - 512];
    const float* Arow = seq + (size_t)src * H + g * 8;
    const _Float16* BF = (mt < 32) ? WSF : WEF;
    f32x4 acc0 = {0.f, 0.f, 0.f, 0.f}, acc1 = acc0;
    float4 v0 = *(const float4*)(Arow);
    float4 v1 = *(const float4*)(Arow + 4);
    half8 b0 = *(const half8*)(BF + ((size_t)(nt0 * 24) * 64 + lane) * 8);
    half8 b1 = *(const half8*)(BF + ((size_t)((nt0 + 1) * 24) * 64 + lane) * 8);
    for (int kt = 0; kt < 24; ++kt) {
        float4 nv0, nv1;
        half8 nb0, nb1;
        if (kt < 23) {
            nv0 = *(const float4*)(Arow + (kt + 1) * 32);
            nv1 = *(const float4*)(Arow + (kt + 1) * 32 + 4);
            nb0 = *(const half8*)(BF + ((size_t)(nt0 * 24 + kt + 1) * 64 + lane) * 8);
            nb1 = *(const half8*)(BF + ((size_t)((nt0 + 1) * 24 + kt + 1) * 64 + lane) * 8);
        }
        half8 a = {(_Float16)v0.x, (_Float16)v0.y, (_Float16)v0.z, (_Float16)v0.w,
                   (_Float16)v1.x, (_Float16)v1.y, (_Float16)v1.z, (_Float16)v1.w};
        acc0 = __builtin_amdgcn_mfma_f32_16x16x32_f16(a, b0, acc0, 0, 0, 0);
        acc1 = __builtin_amdgcn_mfma_f32_16x16x32_f16(a, b1, acc1, 0, 0, 0);
        if (kt < 23) { v0 = nv0; v1 = nv1; b0 = nb0; b1 = nb1; }
    }
    const int c = lane & 15, quad = lane >> 4;
#pragma unroll
    for (int r = 0; r < 4; ++r) {
        const int row = mt * 16 + quad * 4 + r;
        SEH[(size_t)row * H + nt0 * 16 + c] = (_Float16)acc0[r];
        SEH[(size_t)row * H + (nt0 + 1) * 16 + c] = (_Float16)acc1[r];
    }
}

// RKP2[kh] = SEH-half @ W_out-half via f16 MFMA, reg-pipelined. grid (32, 6, 2)
__global__ __launch_bounds__(256) void k_gemm2(const _Float16* __restrict__ SEH,
    const _Float16* __restrict__ WOF, float* __restrict__ RKP2) {
    const int mt = blockIdx.x, kh = blockIdx.z;
    const int wave = threadIdx.x >> 6, lane = threadIdx.x & 63;
    const int nt0 = blockIdx.y * 8 + wave * 2;
    const _Float16* Arow = SEH + (size_t)(kh * 512 + mt * 16 + (lane & 15)) * H + (lane >> 4) * 8;
    const _Float16* B0 = WOF + ((size_t)(nt0 * 48 + kh * 24) * 64 + lane) * 8;
    const _Float16* B1 = WOF + ((size_t)((nt0 + 1) * 48 + kh * 24) * 64 + lane) * 8;
    f32x4 acc0 = {0.f, 0.f, 0.f, 0.f}, acc1 = acc0;
    half8 a = *(const half8*)(Arow);
    half8 b0 = *(const half8*)(B0);
    half8 b1 = *(const half8*)(B1);
    for (int kt2 = 0; kt2 < 24; ++kt2) {
        half8 na, nb0, nb1;
        if (kt2 < 23) {
            na = *(const half8*)(Arow + (kt2 + 1) * 32);
            nb0 = *(const half8*)(B0 + (size_t)(kt2 + 1) * 512);
            nb1 = *(const half8*)(B1 + (size_t)(kt2 + 1) * 512);
        }
        acc0 = __builtin_amdgcn_mfma_f32_16x16x32_f16(a, b0, acc0, 0, 0, 0);
        acc1 = __builtin_amdgcn_mfma_f32_16x16x32_f16(a, b1, acc1, 0, 0, 0);
        if (kt2 < 23) { a = na; b0 = nb0; b1 = nb1; }
    }
    const int c = lane & 15, quad = lane >> 4;
    float* dst = RKP2 + (size_t)kh * 512 * H;
#pragma unroll
    for (int r = 0; r < 4; ++r) {
        const int row = mt * 16 + quad * 4 + r;
        dst[(size_t)row * H + nt0 * 16 + c] = acc0[r];
        dst[(size_t)row * H + (nt0 + 1) * 16 + c] = acc1[r];
    }
}

// U/V partials via f16 MFMA with FUSED fin: block (t,kh) reconstructs its 16x384
// RKH half from RKP2+T into LDS (and writes it to global for k_pair), then MFMAs.
__global__ __launch_bounds__(256) void k_uv3(const float* __restrict__ RKP2,
    const float* __restrict__ T, const int* __restrict__ widI,
    const _Float16* __restrict__ WCF, _Float16* __restrict__ RKH,
    float* __restrict__ UVP) {
    const int t = blockIdx.x, kh = blockIdx.y;
    const int tid = threadIdx.x;
    __shared__ _Float16 sA[16][392];   // stride 392 halves -> minor conflicts only
    // fin: 16 rows x 384 cols (this kh half)
    for (int idx = tid; idx < 16 * 96; idx += 256) {
        const int row = idx / 96, c4 = idx - row * 96;
        const int p = t * 16 + row;
        const int col = kh * 384 + c4 * 4;
        float4 s = *(const float4*)(T + (size_t)widI[p] * H + col);
        float4 v0 = *(const float4*)(RKP2 + (size_t)p * H + col);
        float4 v1 = *(const float4*)(RKP2 + (size_t)(512 + p) * H + col);
        half4 h = {(_Float16)(s.x + v0.x + v1.x), (_Float16)(s.y + v0.y + v1.y),
                   (_Float16)(s.z + v0.z + v1.z), (_Float16)(s.w + v0.w + v1.w)};
        *(half4*)&sA[row][c4 * 4] = h;
        *(half4*)(RKH + (size_t)p * H + col) = h;
    }
    __syncthreads();
    const int wave = tid >> 6, lane = tid & 63;
    const int m = lane & 15, g = lane >> 4;
    f32x4 acc[5];
#pragma unroll
    for (int q = 0; q < 5; ++q) acc[q] = (f32x4){0.f, 0.f, 0.f, 0.f};
    half8 bv[5], nbv[5];
#pragma unroll
    for (int q = 0; q < 5; ++q)
        bv[q] = *(const half8*)(WCF + ((size_t)(((wave * 5 + q) * 24 + kh * 12) * 64 + lane)) * 8);
    for (int kk = 0; kk < 12; ++kk) {
        if (kk < 11) {
            const int kt = kh * 12 + kk + 1;
#pragma unroll
            for (int q = 0; q < 5; ++q)
                nbv[q] = *(const half8*)(WCF + ((size_t)(((wave * 5 + q) * 24 + kt) * 64 + lane)) * 8);
        }
        half8 a = *(const half8*)&sA[m][kk * 32 + g * 8];
#pragma unroll
        for (int q = 0; q < 5; ++q)
            acc[q] = __builtin_amdgcn_mfma_f32_16x16x32_f16(a, bv[q], acc[q], 0, 0, 0);
        if (kk < 11) {
#pragma unroll
            for (int q = 0; q < 5; ++q) bv[q] = nbv[q];
        }
    }
    const int c = lane & 15;
#pragma unroll
    for (int q = 0; q < 5; ++q) {
        const int n = (wave * 5 + q) * 16 + c;
#pragma unroll
        for (int r = 0; r < 4; ++r) {
            const int p = t * 16 + g * 4 + r;
            UVP[((size_t)kh * 512 + p) * 320 + n] = acc[q][r];
        }
    }
}

// Pairwise MFMA v6: 16i x 16j triangular tile (36 pairs x 4 b); wave owns 4 i's
// sharing bv[10] + rj; no LDS/barriers; register double-buffer pipeline.
__global__ __launch_bounds__(256, 1) void k_pair(
    const _Float16* __restrict__ WF, const _Float16* __restrict__ RKH,
    const float* __restrict__ UVP, const float* __restrict__ b1,
    const float* __restrict__ GW, const float* __restrict__ SCAL,
    float* __restrict__ ant) {
    const int b = blockIdx.y;
    int ti = 0, rem = blockIdx.x;
    while (rem >= ti + 1) { rem -= ti + 1; ++ti; }
    const int tj = rem;
    const int wave = threadIdx.x >> 6, lane = threadIdx.x & 63;
    const int g = lane >> 4, c = lane & 15;
    const int i0 = ti * 16 + wave * 4;
    const int j0 = tj * 16;

    const _Float16* Rj = RKH + (size_t)(b * TOPK + j0 + c) * H + g * 8;
    const _Float16* Ri0 = RKH + (size_t)(b * TOPK + i0) * H + g * 8;
    const _Float16* Ri1 = Ri0 + H;
    const _Float16* Ri2 = Ri1 + H;
    const _Float16* Ri3 = Ri2 + H;
    const _Float16* Wl = WF + (size_t)lane * 8;

    f32x4 acc[4][10];
#pragma unroll
    for (int q = 0; q < 4; ++q)
#pragma unroll
        for (int nt = 0; nt < 10; ++nt) acc[q][nt] = (f32x4){0.f, 0.f, 0.f, 0.f};

    half8 bv[10], nbv[10];
    half8 rj, nrj, ri0, ri1, ri2, ri3, nri0, nri1, nri2, nri3;
#pragma unroll
    for (int nt = 0; nt < 10; ++nt) bv[nt] = *(const half8*)(Wl + (size_t)nt * 512);
    rj  = *(const half8*)(Rj);
    ri0 = *(const half8*)(Ri0);
    ri1 = *(const half8*)(Ri1);
    ri2 = *(const half8*)(Ri2);
    ri3 = *(const half8*)(Ri3);

    for (int kt = 0; kt < 24; ++kt) {
        if (kt < 23) {
            const _Float16* wsrc = Wl + (size_t)(kt + 1) * 5120;
#pragma unroll
            for (int nt = 0; nt < 10; ++nt) nbv[nt] = *(const half8*)(wsrc + (size_t)nt * 512);
            nrj  = *(const half8*)(Rj + (kt + 1) * 32);
            nri0 = *(const half8*)(Ri0 + (kt + 1) * 32);
            nri1 = *(const half8*)(Ri1 + (kt + 1) * 32);
            nri2 = *(const half8*)(Ri2 + (kt + 1) * 32);
            nri3 = *(const half8*)(Ri3 + (kt + 1) * 32);
        }
        half8 a0 = ri0 * rj;
        half8 a1 = ri1 * rj;
        half8 a2 = ri2 * rj;
        half8 a3 = ri3 * rj;
#pragma unroll
        for (int nt = 0; nt < 10; ++nt) {
            acc[0][nt] = __builtin_amdgcn_mfma_f32_16x16x32_f16(a0, bv[nt], acc[0][nt], 0, 0, 0);
            acc[1][nt] = __builtin_amdgcn_mfma_f32_16x16x32_f16(a1, bv[nt], acc[1][nt], 0, 0, 0);
            acc[2][nt] = __builtin_amdgcn_mfma_f32_16x16x32_f16(a2, bv[nt], acc[2][nt], 0, 0, 0);
            acc[3][nt] = __builtin_amdgcn_mfma_f32_16x16x32_f16(a3, bv[nt], acc[3][nt], 0, 0, 0);
        }
        if (kt < 23) {
#pragma unroll
            for (int nt = 0; nt < 10; ++nt) bv[nt] = nbv[nt];
            rj = nrj; ri0 = nri0; ri1 = nri1; ri2 = nri2; ri3 = nri3;
        }
    }

    const float Sgw = SCAL[0], C0 = SCAL[1];
    float gw10[10];
#pragma unroll
    for (int nt = 0; nt < 10; ++nt) gw10[nt] = GW[nt * 16 + c];

#pragma unroll
    for (int q = 0; q < 4; ++q) {
        const int i = i0 + q;
        const int pi = b * TOPK + i;
        float u10[10];
#pragma unroll
        for (int nt = 0; nt < 10; ++nt) {
            const int d = nt * 16 + c;
            const float ub = (d < HIDD) ? b1[d] : 0.f;
            u10[nt] = UVP[(size_t)pi * 320 + d] + UVP[(size_t)(512 + pi) * 320 + d] + ub;
        }
#pragma unroll
        for (int r = 0; r < 4; ++r) {
            const int j = j0 + g * 4 + r;
            const int pj = b * TOPK + j;
            const float* Vp0 = UVP + (size_t)pj * 320 + 160;
            const float* Vp1 = UVP + (size_t)(512 + pj) * 320 + 160;
            float s1 = 0.f, s2 = 0.f, s3 = 0.f;
#pragma unroll
            for (int nt = 0; nt < 10; ++nt) {
                const int d = nt * 16 + c;
                float z = acc[q][nt][r] + u10[nt] + Vp0[d] + Vp1[d];
                float h = (d < HIDD && z > 0.f) ? z : 0.f;
                s1 += h;
                s2 += h * h;
                s3 += h * gw10[nt];
            }
#pragma unroll
            for (int off = 1; off < 16; off <<= 1) {
                s1 += __shfl_xor(s1, off, 64);
                s2 += __shfl_xor(s2, off, 64);
                s3 += __shfl_xor(s3, off, 64);
            }
            const float mu = s1 * (1.f / HIDD);
            const float var = s2 * (1.f / HIDD) - mu * mu;
            const float rstd = rsqrtf(var + 1e-5f);
            const float val = rstd * (s3 - mu * Sgw) + C0;
            if (c == 0 && j < i) ant[((size_t)b * TOPK + i) * TOPK + j] = val;
        }
    }
}

extern "C" void kernel_launch(void* const* d_in, const int* in_sizes, int n_in,
                              void* d_out, int out_size, void* d_ws, size_t ws_size,
                              hipStream_t stream) {
    const float* seq      = (const float*)d_in[0];
    const int*   starts   = (const int*)d_in[1];
    const int*   ends     = (const int*)d_in[2];
    const float* W_start  = (const float*)d_in[3];
    const float* b_start  = (const float*)d_in[4];
    const float* W_end    = (const float*)d_in[5];
    const float* b_end    = (const float*)d_in[6];
    const float* width_e  = (const float*)d_in[7];
    const float* W_out    = (const float*)d_in[8];
    const float* b_out    = (const float*)d_in[9];
    const float* w_ment   = (const float*)d_in[10];
    const float* b_ment   = (const float*)d_in[11];
    const float* W1       = (const float*)d_in[12];
    const float* b1       = (const float*)d_in[13];
    const float* ln_g     = (const float*)d_in[14];
    const float* ln_b     = (const float*)d_in[15];
    const float* W2       = (const float*)d_in[16];
    const float* b2       = (const float*)d_in[17];
    float* out = (float*)d_out;
    float* ws  = (float*)d_ws;

    float* Tt    = ws + OFF_T;
    float* biasP = ws + OFF_BIASP;
    float* WOV   = ws + OFF_WOV;
    float* av    = ws + OFF_AV;
    float* cv    = ws + OFF_CV;
    float* tw    = ws + OFF_TW;
    float* PD    = ws + OFF_PD;
    unsigned long long* CANDp = (unsigned long long*)(ws + OFF_CAND);
    int*   fsI   = (int*)(ws + OFF_FS);
    int*   feI   = (int*)(ws + OFF_FE);
    int*   widI  = (int*)(ws + OFF_WID);
    float* UVPp  = ws + OFF_UVP;
    float* GWp   = ws + OFF_GW;
    float* SCALp = ws + OFF_SCAL;
    _Float16* WFp   = (_Float16*)(ws + OFF_WF);
    _Float16* WCFp  = (_Float16*)(ws + OFF_WCF);
    _Float16* WSFp  = (_Float16*)(ws + OFF_WSF);
    _Float16* WEFp  = (_Float16*)(ws + OFF_WEF);
    _Float16* WOFp  = (_Float16*)(ws + OFF_WOF);
    _Float16* SEHp  = (_Float16*)(ws + OFF_SEH);
    _Float16* RKHp  = (_Float16*)(ws + OFF_RKH);
    float* RKP2p = ws + OFF_RKP2;

    kA<<<1805, 256, 0, stream>>>(b_start, b_end, b_out, W_out, w_ment, W1,
                                 ln_g, ln_b, W2, b2, W_start, W_end,
                                 biasP, WOV, WFp, WCFp, WSFp, WEFp, WOFp, GWp, SCALp,
                                 out + OFS_ANT);
    kB<<<417, 256, 0, stream>>>(biasP, width_e, W_out, W_start, W_end, WOV, Tt, av, cv);
    k_posdots<<<2049, 256, 0, stream>>>(seq, av, cv, Tt, w_ment, b_ment, PD, tw);
    k_sort1<<<32, 256, 0, stream>>>(PD, starts, ends, tw, CANDp);
    k_sort2<<<4, 256, 0, stream>>>(CANDp, starts, ends, out, fsI, feI, widI);
    k_gemm1<<<dim3(64, 6), 256, 0, stream>>>(seq, fsI, feI, WSFp, WEFp, SEHp);
    k_gemm2<<<dim3(32, 6, 2), 256, 0, stream>>>(SEHp, WOFp, RKP2p);
    k_uv3<<<dim3(32, 2), 256, 0, stream>>>(RKP2p, Tt, widI, WCFp, RKHp, UVPp);
    k_pair<<<dim3(36, 4), 256, 0, stream>>>(WFp, RKHp, UVPp, b1, GWp, SCALp,
                                            out + OFS_ANT);
}